// Round 19
// baseline (169.569 us; speedup 1.0000x reference)
//
#include <hip/hip_runtime.h>

typedef __bf16 bf16;
typedef __attribute__((ext_vector_type(4))) float f32x4;
typedef __attribute__((ext_vector_type(8))) bf16 bf16x8;
typedef __attribute__((ext_vector_type(4))) bf16 bf16x4;

constexpr int Bc = 4, Sc = 1024, Dc = 1024, Hc = 16, DKc = 64;
// softmax scale 0.125 folded with log2(e): exp(x*0.125) == exp2(x') with
// weights pre-scaled by ESCALE.
#define ESCALE 0.18033688011112042f
#define EXP2F(x) __builtin_amdgcn_exp2f(x)

// ---------------- helpers ----------------

// Stage a 64x64 bf16 tile into swizzled LDS from bf16 or fp32 source (reg path).
// Swizzle: element = r*64 + (c ^ ((r&7)<<3))
__device__ __forceinline__ void stage64(bf16* s, const void* g, int ld, int f32src) {
  const int t = threadIdx.x;
#pragma unroll
  for (int i = 0; i < 2; ++i) {
    const int G = t + i * 256;
    const int r = G >> 3, gr = G & 7;
    bf16x8 o;
    if (f32src) {
      const float* gp = (const float*)g + (long)r * ld + gr * 8;
      const f32x4 a = *(const f32x4*)gp;
      const f32x4 b = *(const f32x4*)(gp + 4);
      o[0]=(bf16)a[0]; o[1]=(bf16)a[1]; o[2]=(bf16)a[2]; o[3]=(bf16)a[3];
      o[4]=(bf16)b[0]; o[5]=(bf16)b[1]; o[6]=(bf16)b[2]; o[7]=(bf16)b[3];
    } else {
      o = *(const bf16x8*)((const bf16*)g + (long)r * ld + gr * 8);
    }
    *(bf16x8*)(s + r * 64 + ((gr * 8) ^ ((r & 7) << 3))) = o;
  }
}

// MFMA operand fragment (16x16x32 bf16) from a swizzled tile (64-col rows).
__device__ __forceinline__ bf16x8 frag_ld(const bf16* s, int row, int kofs) {
  const int lane = threadIdx.x & 63;
  const int c0 = kofs + (((lane >> 4) & 3) << 2);
  const int sw = (row & 7) << 3;
  union { bf16x8 v8; bf16x4 v4[2]; } u;
  u.v4[0] = *(const bf16x4*)(s + row * 64 + (c0 ^ sw));
  u.v4[1] = *(const bf16x4*)(s + row * 64 + ((c0 + 16) ^ sw));
  return u.v8;
}

// direct-to-LDS 16B DMA (vmcnt-counted)
__device__ __forceinline__ void gld16(const bf16* g, bf16* l) {
  __builtin_amdgcn_global_load_lds(
      (const __attribute__((address_space(1))) void*)g,
      (__attribute__((address_space(3))) void*)l, 16, 0, 0);
}

#define WAIT_BAR(vm) do { \
  asm volatile("s_waitcnt vmcnt(" vm ")" ::: "memory"); \
  __builtin_amdgcn_s_barrier(); \
  __builtin_amdgcn_sched_barrier(0); } while (0)

// ---------------- weight transpose (fp32 -> bf16 T), LDS-tiled ----------------
__global__ __launch_bounds__(256) void transpose_weights(
    const float* __restrict__ Wq, const float* __restrict__ Wk,
    const float* __restrict__ Wv, const float* __restrict__ Wc,
    bf16* __restrict__ WqT, bf16* __restrict__ WkT,
    bf16* __restrict__ WvT, bf16* __restrict__ WcT) {
  const int bid = blockIdx.x;
  const float* src; bf16* dst; float scl; int r0;
  if (bid < 256)      { const int hh = bid >> 4; r0 = (bid & 15) * 64;
                        src = Wq + (hh << 16); dst = WqT + (hh << 16); scl = ESCALE; }
  else if (bid < 272) { r0 = (bid - 256) * 64; src = Wk; dst = WkT; scl = 1.f; }
  else if (bid < 288) { r0 = (bid - 272) * 64; src = Wv; dst = WvT; scl = 1.f; }
  else                { r0 = (bid - 288) * 64; src = Wc; dst = WcT; scl = 1.f; }

  __shared__ float tile[64][68];
  const int t = threadIdx.x;
  const int rr = t >> 4, cc = (t & 15) * 4;
#pragma unroll
  for (int i = 0; i < 4; ++i) {
    const f32x4 v = *(const f32x4*)(src + (long)(r0 + rr + i * 16) * 64 + cc);
    *(f32x4*)(&tile[rr + i * 16][cc]) = v;
  }
  __syncthreads();
#pragma unroll
  for (int i = 0; i < 2; ++i) {
    const int g = t + i * 256, orow = g >> 3, oc = (g & 7) * 8;
    bf16x8 o;
#pragma unroll
    for (int jj = 0; jj < 8; ++jj) o[jj] = (bf16)(tile[oc + jj][orow] * scl);
    *(bf16x8*)(dst + (long)orow * 1024 + r0 + oc) = o;
  }
}

// ---------------- merged projection: Q 128x128-tile + K/V 64x64-tile -------
__global__ __launch_bounds__(256) void proj_kernel(
    const float* __restrict__ query, const float* __restrict__ key,
    const float* __restrict__ value, const bf16* __restrict__ WqT,
    const bf16* __restrict__ WkT, const bf16* __restrict__ WvT,
    const float* __restrict__ bq, const float* __restrict__ bk,
    const float* __restrict__ bv, bf16* __restrict__ q_cat,
    bf16* __restrict__ k_proj, bf16* __restrict__ vTp) {
  __shared__ bf16 sA[2][8192];
  __shared__ bf16 sB[2][8192];
  const int bid = blockIdx.x;
  const int t = threadIdx.x;
  const int lane = t & 63;
  const int w = t >> 6;

  if (bid < 256) {
    // ---------- Q path: 128x128 tile ----------
    const int m0 = (bid >> 3) << 7, n0 = (bid & 7) << 7;
    const int wr = w >> 1, wc = w & 1;

    f32x4 acc[4][4];
#pragma unroll
    for (int mi = 0; mi < 4; ++mi)
#pragma unroll
      for (int ni = 0; ni < 4; ++ni) acc[mi][ni] = (f32x4){0.f, 0.f, 0.f, 0.f};

    auto sQA = [&](int p, int kk) {       // query fp32 [128][64] -> bf16 swz
      const int r = t >> 1, ch = (t & 1) << 5;
      const float* gp = query + (long)(m0 + r) * 1024 + kk + ch;
#pragma unroll
      for (int j = 0; j < 4; ++j) {
        const f32x4 a = *(const f32x4*)(gp + j * 8);
        const f32x4 b = *(const f32x4*)(gp + j * 8 + 4);
        bf16x8 o;
        o[0]=(bf16)a[0]; o[1]=(bf16)a[1]; o[2]=(bf16)a[2]; o[3]=(bf16)a[3];
        o[4]=(bf16)b[0]; o[5]=(bf16)b[1]; o[6]=(bf16)b[2]; o[7]=(bf16)b[3];
        *(bf16x8*)(&sA[p][r * 64 + ((ch + j * 8) ^ ((r & 7) << 3))]) = o;
      }
    };
    auto sQB = [&](int p, int kk) {       // WqT bf16 [128][64] -> swz
#pragma unroll
      for (int i = 0; i < 4; ++i) {
        const int G = t + i * 256, r = G >> 3, c8 = (G & 7) << 3;
        const bf16x8 v = *(const bf16x8*)(WqT + (long)(n0 + r) * 1024 + kk + c8);
        *(bf16x8*)(&sB[p][r * 64 + (c8 ^ ((r & 7) << 3))]) = v;
      }
    };

    sQA(0, 0); sQB(0, 0);
    __syncthreads();
    for (int it = 0; it < 16; ++it) {
      const int p = it & 1;
      if (it < 15) { sQA(p ^ 1, (it + 1) * 64); sQB(p ^ 1, (it + 1) * 64); }
#pragma unroll
      for (int ks = 0; ks < 2; ++ks) {
        bf16x8 af[4], bfr[4];
#pragma unroll
        for (int mi = 0; mi < 4; ++mi)
          af[mi] = frag_ld(sA[p], wr * 64 + mi * 16 + (lane & 15), ks * 32);
#pragma unroll
        for (int ni = 0; ni < 4; ++ni)
          bfr[ni] = frag_ld(sB[p], wc * 64 + ni * 16 + (lane & 15), ks * 32);
#pragma unroll
        for (int mi = 0; mi < 4; ++mi)
#pragma unroll
          for (int ni = 0; ni < 4; ++ni)
            acc[mi][ni] = __builtin_amdgcn_mfma_f32_16x16x32_bf16(af[mi], bfr[ni], acc[mi][ni], 0, 0, 0);
      }
      __syncthreads();
    }

    const int rb = m0 + wr * 64 + ((lane >> 4) << 2);
#pragma unroll
    for (int ni = 0; ni < 4; ++ni) {
      const int col = n0 + wc * 64 + ni * 16 + (lane & 15);
      const float bn = bq[col] * ESCALE;
#pragma unroll
      for (int mi = 0; mi < 4; ++mi)
#pragma unroll
        for (int r4 = 0; r4 < 4; ++r4)
          q_cat[(long)(rb + mi * 16 + r4) * 1024 + col] = (bf16)(acc[mi][ni][r4] + bn);
    }
    return;
  }

  // ---------- K / V path: 64x64 tile ----------
  const void* A; const void* BT; bf16* C; const float* bias;
  int m0, n0, ldA, ldBT, ldC, aF32, bF32, biasM;
  if (bid < 320) {
    m0 = (bid - 256) << 6; n0 = 0;
    A = key;    ldA = 1024; aF32 = 1;
    BT = WkT;   ldBT = 1024; bF32 = 0;
    C = k_proj; ldC = 64; bias = bk; biasM = 0;
  } else {
    const int j = bid - 320;
    m0 = 0; n0 = (j & 15) << 6;
    A = WvT; ldA = 1024; aF32 = 0;
    BT = value + ((long)(j >> 4) << 20); ldBT = 1024; bF32 = 1;
    C = vTp + ((long)(j >> 4) << 16); ldC = 1024; bias = bv; biasM = 1;
  }

  f32x4 acc[4];
#pragma unroll
  for (int nb = 0; nb < 4; ++nb) acc[nb] = (f32x4){0.f, 0.f, 0.f, 0.f};

  stage64(sA[0], aF32 ? (const void*)((const float*)A + (long)m0 * ldA)
                      : (const void*)((const bf16*)A + (long)m0 * ldA), ldA, aF32);
  stage64(sB[0], bF32 ? (const void*)((const float*)BT + (long)n0 * ldBT)
                      : (const void*)((const bf16*)BT + (long)n0 * ldBT), ldBT, bF32);
  __syncthreads();

  for (int it = 0; it < 16; ++it) {
    const int p = it & 1;
    if (it < 15) {
      const int kk = (it + 1) * 64;
      stage64(sA[p ^ 1], aF32 ? (const void*)((const float*)A + (long)m0 * ldA + kk)
                              : (const void*)((const bf16*)A + (long)m0 * ldA + kk), ldA, aF32);
      stage64(sB[p ^ 1], bF32 ? (const void*)((const float*)BT + (long)n0 * ldBT + kk)
                              : (const void*)((const bf16*)BT + (long)n0 * ldBT + kk), ldBT, bF32);
    }
#pragma unroll
    for (int ks = 0; ks < 2; ++ks) {
      const bf16x8 af = frag_ld(sA[p], 16 * w + (lane & 15), ks * 32);
#pragma unroll
      for (int nb = 0; nb < 4; ++nb) {
        const bf16x8 bfr = frag_ld(sB[p], nb * 16 + (lane & 15), ks * 32);
        acc[nb] = __builtin_amdgcn_mfma_f32_16x16x32_bf16(af, bfr, acc[nb], 0, 0, 0);
      }
    }
    __syncthreads();
  }

  const int rbase = m0 + 16 * w + ((lane >> 4) << 2);
#pragma unroll
  for (int nb = 0; nb < 4; ++nb) {
    const int col = n0 + nb * 16 + (lane & 15);
    const float bn = biasM ? 0.f : bias[col];
#pragma unroll
    for (int r = 0; r < 4; ++r) {
      const int row = rbase + r;
      C[(long)row * ldC + col] = (bf16)(acc[nb][r] + (biasM ? bias[row] : bn));
    }
  }
}

// ---------------- combine GEMM: split-K=4 partials + reduce ----------------
__global__ __launch_bounds__(256) void combine_kernel(
    const bf16* __restrict__ concat, const bf16* __restrict__ WcT,
    float* __restrict__ part) {
  const int ks = blockIdx.x >> 6;
  const int m0 = (blockIdx.x & 63) * 64;
  const int k0 = ks * 256;
  __shared__ bf16 sA[2][4096];
  __shared__ bf16 sB[2][4096];
  const int lane = threadIdx.x & 63;
  const int w = threadIdx.x >> 6;

  f32x4 acc[4];
#pragma unroll
  for (int nb = 0; nb < 4; ++nb) acc[nb] = (f32x4){0.f, 0.f, 0.f, 0.f};

  stage64(sA[0], concat + (long)m0 * 1024 + k0, 1024, 0);
  stage64(sB[0], WcT + k0, 1024, 0);
  __syncthreads();
  for (int it = 0; it < 4; ++it) {
    const int p = it & 1;
    if (it < 3) {
      const int kk = k0 + (it + 1) * 64;
      stage64(sA[p ^ 1], concat + (long)m0 * 1024 + kk, 1024, 0);
      stage64(sB[p ^ 1], WcT + kk, 1024, 0);
    }
#pragma unroll
    for (int ksl = 0; ksl < 2; ++ksl) {
      const bf16x8 af = frag_ld(sA[p], 16 * w + (lane & 15), ksl * 32);
#pragma unroll
      for (int nb = 0; nb < 4; ++nb) {
        const bf16x8 bfr = frag_ld(sB[p], nb * 16 + (lane & 15), ksl * 32);
        acc[nb] = __builtin_amdgcn_mfma_f32_16x16x32_bf16(af, bfr, acc[nb], 0, 0, 0);
      }
    }
    __syncthreads();
  }
  const int rbase = m0 + 16 * w + ((lane >> 4) << 2);
  float* pb = part + (long)ks * 262144;
#pragma unroll
  for (int nb = 0; nb < 4; ++nb) {
    const int col = nb * 16 + (lane & 15);
#pragma unroll
    for (int r = 0; r < 4; ++r)
      pb[(long)(rbase + r) * 64 + col] = acc[nb][r];
  }
}

__global__ __launch_bounds__(256) void reduce_combine(
    const float* __restrict__ part, const float* __restrict__ bc,
    float* __restrict__ out0) {
  const int i = blockIdx.x * 256 + threadIdx.x;
  out0[i] = part[i] + part[i + 262144] + part[i + 524288] + part[i + 786432]
          + bc[i & 63];
}

// ---------------- fused attention (R13 + pass-B 2-tile iterations) --------
// 1024 blocks, 2 waves x 32 q-rows. LDS: 8 x 4KB buffers (32KB, same total).
// Pass A: K-only 4-ring over bufs[0..3], prefetch 3 (R13, unchanged).
// Pass B: 2 tiles per barrier-pair (8 iterations). K batches ping-pong in
// bufs {2p,2p+1}, V in bufs {4+2p,4+2p+1}. Per iter FIFO: [D(it+1)=16,
// compute 2 tiles, S(it)=16] -> WAIT_BAR("16") keeps stores floating a full
// (2x-long) iteration and gives DMAs the whole compute phase to land.
__global__ __launch_bounds__(128, 4) void attn_kernel(
    const bf16* __restrict__ q_cat, const bf16* __restrict__ k_proj,
    const bf16* __restrict__ vT, float* __restrict__ attn_out,
    bf16* __restrict__ concat) {
  const int s0 = blockIdx.x * 64;
  const int h = blockIdx.y, b = blockIdx.z;
  const int t = threadIdx.x;               // 0..127
  const int lane = t & 63;
  const int w = t >> 6;                    // 0,1

  __shared__ bf16 sKV[8][4096];

  const bf16* kp = k_proj + (long)b * Sc * DKc;
  const bf16* vp = vT + (long)b * DKc * Sc;
  float* ao = attn_out + ((long)(b * Hc + h) * Sc + s0) * Sc;
  bf16* co = concat + (long)(b * Sc + s0) * (Hc * DKc) + h * DKc;

  const int c0q = (lane >> 4) << 2;
  const int wq0 = w * 32;

  const int rloc = t >> 3;
  const int col8 = ((t & 7) ^ (rloc & 7)) << 3;
  const int ldsw = w << 9;

  auto stageK = [&](int buf, int tt) {     // 4 DMAs per wave
#pragma unroll
    for (int c = 0; c < 4; ++c)
      gld16(kp + ((long)tt << 12) + (c * 16 + rloc) * 64 + col8,
            &sKV[buf][c * 1024 + ldsw]);
  };
  auto stageV = [&](int buf, int tt) {     // 4 DMAs per wave
#pragma unroll
    for (int c = 0; c < 4; ++c)
      gld16(vp + (long)(c * 16 + rloc) * 1024 + tt * 64 + col8,
            &sKV[buf][c * 1024 + ldsw]);
  };

  // Q fragments for both q-groups (pre-scaled by ESCALE via WqT)
  bf16x8 qf[2][2];
#pragma unroll
  for (int qg = 0; qg < 2; ++qg) {
    const bf16* qrow = q_cat + (long)(b * Sc + s0 + wq0 + qg * 16 + (lane & 15)) * 1024 + h * 64;
    union { bf16x8 v8; bf16x4 v4[2]; } a, c;
    a.v4[0] = *(const bf16x4*)(qrow + c0q);
    a.v4[1] = *(const bf16x4*)(qrow + c0q + 16);
    c.v4[0] = *(const bf16x4*)(qrow + c0q + 32);
    c.v4[1] = *(const bf16x4*)(qrow + c0q + 48);
    qf[qg][0] = a.v8; qf[qg][1] = c.v8;
  }

  // ---- pass A: lsum only; 4-ring, prefetch depth 3 (R13) ----
  stageK(0, 0); stageK(1, 1); stageK(2, 2);
  WAIT_BAR("8");                           // 12 out -> <=8: batch 0 retired
  float lsum[2] = {0.f, 0.f};
  for (int tc = 0; tc < 16; ++tc) {
    if (tc + 3 < 16) stageK((tc + 3) & 3, tc + 3);
    const bf16* kb = &sKV[tc & 3][0];
    bf16x8 kf[2][4];
#pragma unroll
    for (int ks = 0; ks < 2; ++ks)
#pragma unroll
      for (int nb = 0; nb < 4; ++nb)
        kf[ks][nb] = frag_ld(kb, nb * 16 + (lane & 15), ks * 32);
#pragma unroll
    for (int qg = 0; qg < 2; ++qg) {
      f32x4 sc[4];
#pragma unroll
      for (int nb = 0; nb < 4; ++nb) sc[nb] = (f32x4){0.f, 0.f, 0.f, 0.f};
#pragma unroll
      for (int ks = 0; ks < 2; ++ks)
#pragma unroll
        for (int nb = 0; nb < 4; ++nb)
          sc[nb] = __builtin_amdgcn_mfma_f32_16x16x32_bf16(kf[ks][nb], qf[qg][ks], sc[nb], 0, 0, 0);
#pragma unroll
      for (int nb = 0; nb < 4; ++nb)
#pragma unroll
        for (int r = 0; r < 4; ++r) lsum[qg] += EXP2F(sc[nb][r]);
    }
    // need buf (tc+1) ready next iter: allow only batches > tc+1 in flight
    if (tc < 13)       WAIT_BAR("8");
    else if (tc == 13) WAIT_BAR("4");
    else if (tc == 14) WAIT_BAR("0");
  }
  __builtin_amdgcn_s_barrier();            // pass A fully done before re-staging

#pragma unroll
  for (int qg = 0; qg < 2; ++qg) {
    lsum[qg] += __shfl_xor(lsum[qg], 16, 64);
    lsum[qg] += __shfl_xor(lsum[qg], 32, 64);
  }
  const float invl0 = 1.f / lsum[0], invl1 = 1.f / lsum[1];

  f32x4 oacc[2][4];
#pragma unroll
  for (int qg = 0; qg < 2; ++qg)
#pragma unroll
    for (int nb = 0; nb < 4; ++nb) oacc[qg][nb] = (f32x4){0.f, 0.f, 0.f, 0.f};

  // ---- pass B: 2 tiles per barrier-pair (8 iterations) ----
  // batch s in slot p: K tiles -> bufs {2p, 2p+1}; V tiles -> {4+2p, 5+2p}
  stageK(0, 0); stageK(1, 1); stageV(4, 0); stageV(5, 1);   // batch 0 -> slot 0
  WAIT_BAR("0");
  for (int it = 0; it < 8; ++it) {
    const int p = it & 1;
    if (it < 7) {                          // batch it+1 -> slot p^1
      const int q = p ^ 1, t0 = 2 * (it + 1);
      stageK(2 * q, t0); stageK(2 * q + 1, t0 + 1);
      stageV(4 + 2 * q, t0); stageV(5 + 2 * q, t0 + 1);
    }
#pragma unroll
    for (int tt = 0; tt < 2; ++tt) {
      const int tc = 2 * it + tt;
      bf16x8 kf[2][4];
#pragma unroll
      for (int ks = 0; ks < 2; ++ks)
#pragma unroll
        for (int nb = 0; nb < 4; ++nb)
          kf[ks][nb] = frag_ld(&sKV[2 * p + tt][0], nb * 16 + (lane & 15), ks * 32);
      bf16x8 pa[2][2];
#pragma unroll
      for (int qg = 0; qg < 2; ++qg) {
        f32x4 sc[4];
#pragma unroll
        for (int nb = 0; nb < 4; ++nb) sc[nb] = (f32x4){0.f, 0.f, 0.f, 0.f};
#pragma unroll
        for (int ks = 0; ks < 2; ++ks)
#pragma unroll
          for (int nb = 0; nb < 4; ++nb)
            sc[nb] = __builtin_amdgcn_mfma_f32_16x16x32_bf16(kf[ks][nb], qf[qg][ks], sc[nb], 0, 0, 0);
        const float invl = qg ? invl1 : invl0;
        float* aobase = ao + (long)(wq0 + qg * 16 + (lane & 15)) * Sc + tc * 64 + c0q;
        float e[4][4];
#pragma unroll
        for (int nb = 0; nb < 4; ++nb) {
#pragma unroll
          for (int r = 0; r < 4; ++r) e[nb][r] = EXP2F(sc[nb][r]);
          f32x4 av;
#pragma unroll
          for (int r = 0; r < 4; ++r) av[r] = e[nb][r] * invl;
          *(f32x4*)(aobase + nb * 16) = av;
        }
#pragma unroll
        for (int ks = 0; ks < 2; ++ks)
#pragma unroll
          for (int jj = 0; jj < 4; ++jj) {
            pa[qg][ks][jj]     = (bf16)e[2 * ks][jj];
            pa[qg][ks][4 + jj] = (bf16)e[2 * ks + 1][jj];
          }
      }
#pragma unroll
      for (int ks = 0; ks < 2; ++ks)
#pragma unroll
        for (int nb = 0; nb < 4; ++nb) {
          const bf16x8 vf = frag_ld(&sKV[4 + 2 * p + tt][0], nb * 16 + (lane & 15), ks * 32);
          oacc[0][nb] = __builtin_amdgcn_mfma_f32_16x16x32_bf16(pa[0][ks], vf, oacc[0][nb], 0, 0, 0);
          oacc[1][nb] = __builtin_amdgcn_mfma_f32_16x16x32_bf16(pa[1][ks], vf, oacc[1][nb], 0, 0, 0);
        }
    }
    // FIFO: D(it+1)=16 retired <=> only S(it)=16 newer events in flight
    if (it < 7) WAIT_BAR("16");
  }

  // epilogue: normalize PV, store concat slice
#pragma unroll
  for (int qg = 0; qg < 2; ++qg) {
    const float invl = qg ? invl1 : invl0;
    float invo[4];
#pragma unroll
    for (int r = 0; r < 4; ++r) invo[r] = __shfl(invl, c0q + r, 64);
#pragma unroll
    for (int nb = 0; nb < 4; ++nb) {
#pragma unroll
      for (int r = 0; r < 4; ++r) {
        const int row = wq0 + qg * 16 + c0q + r;
        const int col = nb * 16 + (lane & 15);
        co[(long)row * (Hc * DKc) + col] = (bf16)(oacc[qg][nb][r] * invo[r]);
      }
    }
  }
}

// ---------------- launcher ----------------

extern "C" void kernel_launch(void* const* d_in, const int* in_sizes, int n_in,
                              void* d_out, int out_size, void* d_ws, size_t ws_size,
                              hipStream_t stream) {
  const float* query = (const float*)d_in[0];
  const float* key   = (const float*)d_in[1];
  const float* value = (const float*)d_in[2];
  const float* Wq = (const float*)d_in[3];
  const float* bq = (const float*)d_in[4];
  const float* Wk = (const float*)d_in[5];
  const float* bk = (const float*)d_in[6];
  const float* Wv = (const float*)d_in[7];
  const float* bv = (const float*)d_in[8];
  const float* Wc = (const float*)d_in[9];
  const float* bc = (const float*)d_in[10];

  bf16* WqT    = (bf16*)d_ws;              // [1024][1024] (pre-scaled ESCALE)
  bf16* WkT    = WqT + 1048576;            // [64][1024]
  bf16* WvT    = WkT + 65536;
  bf16* WcT    = WvT + 65536;              // [64][1024]
  bf16* q_cat  = WcT + 65536;              // [4096][1024]
  bf16* k_proj = q_cat + 4194304;          // [4096][64]
  bf16* vTp    = k_proj + 262144;          // [B][64][1024]
  bf16* concat = vTp + 262144;             // [4096][1024]
  float* part  = (float*)(concat + 4194304); // [4][4096][64] fp32 partials

  float* out0 = (float*)d_out;                       // [B][S][DK]
  float* attn = out0 + (long)Bc * Sc * DKc;          // [B][H][S][S]

  transpose_weights<<<304, 256, 0, stream>>>(Wq, Wk, Wv, Wc, WqT, WkT, WvT, WcT);

  proj_kernel<<<384, 256, 0, stream>>>(query, key, value, WqT, WkT, WvT,
                                       bq, bk, bv, q_cat, k_proj, vTp);

  attn_kernel<<<dim3(16, 16, 4), 128, 0, stream>>>(q_cat, k_proj, vTp, attn, concat);

  combine_kernel<<<256, 256, 0, stream>>>(concat, WcT, part);
  reduce_combine<<<1024, 256, 0, stream>>>(part, bc, out0);
}

// Round 20
// 154.773 us; speedup vs baseline: 1.0956x; 1.0956x over previous
//
#include <hip/hip_runtime.h>

typedef __bf16 bf16;
typedef __attribute__((ext_vector_type(4))) float f32x4;
typedef __attribute__((ext_vector_type(8))) bf16 bf16x8;
typedef __attribute__((ext_vector_type(4))) bf16 bf16x4;

constexpr int Bc = 4, Sc = 1024, Dc = 1024, Hc = 16, DKc = 64;
// softmax scale 0.125 folded with log2(e): exp(x*0.125) == exp2(x') with
// weights pre-scaled by ESCALE.
#define ESCALE 0.18033688011112042f
#define EXP2F(x) __builtin_amdgcn_exp2f(x)

// ---------------- helpers ----------------

// Stage a 64x64 bf16 tile into swizzled LDS from bf16 or fp32 source (reg path).
// Swizzle: element = r*64 + (c ^ ((r&7)<<3))
__device__ __forceinline__ void stage64(bf16* s, const void* g, int ld, int f32src) {
  const int t = threadIdx.x;
#pragma unroll
  for (int i = 0; i < 2; ++i) {
    const int G = t + i * 256;
    const int r = G >> 3, gr = G & 7;
    bf16x8 o;
    if (f32src) {
      const float* gp = (const float*)g + (long)r * ld + gr * 8;
      const f32x4 a = *(const f32x4*)gp;
      const f32x4 b = *(const f32x4*)(gp + 4);
      o[0]=(bf16)a[0]; o[1]=(bf16)a[1]; o[2]=(bf16)a[2]; o[3]=(bf16)a[3];
      o[4]=(bf16)b[0]; o[5]=(bf16)b[1]; o[6]=(bf16)b[2]; o[7]=(bf16)b[3];
    } else {
      o = *(const bf16x8*)((const bf16*)g + (long)r * ld + gr * 8);
    }
    *(bf16x8*)(s + r * 64 + ((gr * 8) ^ ((r & 7) << 3))) = o;
  }
}

// MFMA operand fragment (16x16x32 bf16) from a swizzled tile (64-col rows).
__device__ __forceinline__ bf16x8 frag_ld(const bf16* s, int row, int kofs) {
  const int lane = threadIdx.x & 63;
  const int c0 = kofs + (((lane >> 4) & 3) << 2);
  const int sw = (row & 7) << 3;
  union { bf16x8 v8; bf16x4 v4[2]; } u;
  u.v4[0] = *(const bf16x4*)(s + row * 64 + (c0 ^ sw));
  u.v4[1] = *(const bf16x4*)(s + row * 64 + ((c0 + 16) ^ sw));
  return u.v8;
}

// direct-to-LDS 16B DMA (vmcnt-counted)
__device__ __forceinline__ void gld16(const bf16* g, bf16* l) {
  __builtin_amdgcn_global_load_lds(
      (const __attribute__((address_space(1))) void*)g,
      (__attribute__((address_space(3))) void*)l, 16, 0, 0);
}

#define WAIT_BAR(vm) do { \
  asm volatile("s_waitcnt vmcnt(" vm ")" ::: "memory"); \
  __builtin_amdgcn_s_barrier(); \
  __builtin_amdgcn_sched_barrier(0); } while (0)

// ---------------- weight transpose (fp32 -> bf16 T), LDS-tiled ----------------
__global__ __launch_bounds__(256) void transpose_weights(
    const float* __restrict__ Wq, const float* __restrict__ Wk,
    const float* __restrict__ Wv, const float* __restrict__ Wc,
    bf16* __restrict__ WqT, bf16* __restrict__ WkT,
    bf16* __restrict__ WvT, bf16* __restrict__ WcT) {
  const int bid = blockIdx.x;
  const float* src; bf16* dst; float scl; int r0;
  if (bid < 256)      { const int hh = bid >> 4; r0 = (bid & 15) * 64;
                        src = Wq + (hh << 16); dst = WqT + (hh << 16); scl = ESCALE; }
  else if (bid < 272) { r0 = (bid - 256) * 64; src = Wk; dst = WkT; scl = 1.f; }
  else if (bid < 288) { r0 = (bid - 272) * 64; src = Wv; dst = WvT; scl = 1.f; }
  else                { r0 = (bid - 288) * 64; src = Wc; dst = WcT; scl = 1.f; }

  __shared__ float tile[64][68];
  const int t = threadIdx.x;
  const int rr = t >> 4, cc = (t & 15) * 4;
#pragma unroll
  for (int i = 0; i < 4; ++i) {
    const f32x4 v = *(const f32x4*)(src + (long)(r0 + rr + i * 16) * 64 + cc);
    *(f32x4*)(&tile[rr + i * 16][cc]) = v;
  }
  __syncthreads();
#pragma unroll
  for (int i = 0; i < 2; ++i) {
    const int g = t + i * 256, orow = g >> 3, oc = (g & 7) * 8;
    bf16x8 o;
#pragma unroll
    for (int jj = 0; jj < 8; ++jj) o[jj] = (bf16)(tile[oc + jj][orow] * scl);
    *(bf16x8*)(dst + (long)orow * 1024 + r0 + oc) = o;
  }
}

// ---------------- merged projection: Q 128x128-tile + K/V 64x64-tile -------
__global__ __launch_bounds__(256) void proj_kernel(
    const float* __restrict__ query, const float* __restrict__ key,
    const float* __restrict__ value, const bf16* __restrict__ WqT,
    const bf16* __restrict__ WkT, const bf16* __restrict__ WvT,
    const float* __restrict__ bq, const float* __restrict__ bk,
    const float* __restrict__ bv, bf16* __restrict__ q_cat,
    bf16* __restrict__ k_proj, bf16* __restrict__ vTp) {
  __shared__ bf16 sA[2][8192];
  __shared__ bf16 sB[2][8192];
  const int bid = blockIdx.x;
  const int t = threadIdx.x;
  const int lane = t & 63;
  const int w = t >> 6;

  if (bid < 256) {
    // ---------- Q path: 128x128 tile ----------
    const int m0 = (bid >> 3) << 7, n0 = (bid & 7) << 7;
    const int wr = w >> 1, wc = w & 1;

    f32x4 acc[4][4];
#pragma unroll
    for (int mi = 0; mi < 4; ++mi)
#pragma unroll
      for (int ni = 0; ni < 4; ++ni) acc[mi][ni] = (f32x4){0.f, 0.f, 0.f, 0.f};

    auto sQA = [&](int p, int kk) {       // query fp32 [128][64] -> bf16 swz
      const int r = t >> 1, ch = (t & 1) << 5;
      const float* gp = query + (long)(m0 + r) * 1024 + kk + ch;
#pragma unroll
      for (int j = 0; j < 4; ++j) {
        const f32x4 a = *(const f32x4*)(gp + j * 8);
        const f32x4 b = *(const f32x4*)(gp + j * 8 + 4);
        bf16x8 o;
        o[0]=(bf16)a[0]; o[1]=(bf16)a[1]; o[2]=(bf16)a[2]; o[3]=(bf16)a[3];
        o[4]=(bf16)b[0]; o[5]=(bf16)b[1]; o[6]=(bf16)b[2]; o[7]=(bf16)b[3];
        *(bf16x8*)(&sA[p][r * 64 + ((ch + j * 8) ^ ((r & 7) << 3))]) = o;
      }
    };
    auto sQB = [&](int p, int kk) {       // WqT bf16 [128][64] -> swz
#pragma unroll
      for (int i = 0; i < 4; ++i) {
        const int G = t + i * 256, r = G >> 3, c8 = (G & 7) << 3;
        const bf16x8 v = *(const bf16x8*)(WqT + (long)(n0 + r) * 1024 + kk + c8);
        *(bf16x8*)(&sB[p][r * 64 + (c8 ^ ((r & 7) << 3))]) = v;
      }
    };

    sQA(0, 0); sQB(0, 0);
    __syncthreads();
    for (int it = 0; it < 16; ++it) {
      const int p = it & 1;
      if (it < 15) { sQA(p ^ 1, (it + 1) * 64); sQB(p ^ 1, (it + 1) * 64); }
#pragma unroll
      for (int ks = 0; ks < 2; ++ks) {
        bf16x8 af[4], bfr[4];
#pragma unroll
        for (int mi = 0; mi < 4; ++mi)
          af[mi] = frag_ld(sA[p], wr * 64 + mi * 16 + (lane & 15), ks * 32);
#pragma unroll
        for (int ni = 0; ni < 4; ++ni)
          bfr[ni] = frag_ld(sB[p], wc * 64 + ni * 16 + (lane & 15), ks * 32);
#pragma unroll
        for (int mi = 0; mi < 4; ++mi)
#pragma unroll
          for (int ni = 0; ni < 4; ++ni)
            acc[mi][ni] = __builtin_amdgcn_mfma_f32_16x16x32_bf16(af[mi], bfr[ni], acc[mi][ni], 0, 0, 0);
      }
      __syncthreads();
    }

    const int rb = m0 + wr * 64 + ((lane >> 4) << 2);
#pragma unroll
    for (int ni = 0; ni < 4; ++ni) {
      const int col = n0 + wc * 64 + ni * 16 + (lane & 15);
      const float bn = bq[col] * ESCALE;
#pragma unroll
      for (int mi = 0; mi < 4; ++mi)
#pragma unroll
        for (int r4 = 0; r4 < 4; ++r4)
          q_cat[(long)(rb + mi * 16 + r4) * 1024 + col] = (bf16)(acc[mi][ni][r4] + bn);
    }
    return;
  }

  // ---------- K / V path: 64x64 tile ----------
  const void* A; const void* BT; bf16* C; const float* bias;
  int m0, n0, ldA, ldBT, ldC, aF32, bF32, biasM;
  if (bid < 320) {
    m0 = (bid - 256) << 6; n0 = 0;
    A = key;    ldA = 1024; aF32 = 1;
    BT = WkT;   ldBT = 1024; bF32 = 0;
    C = k_proj; ldC = 64; bias = bk; biasM = 0;
  } else {
    const int j = bid - 320;
    m0 = 0; n0 = (j & 15) << 6;
    A = WvT; ldA = 1024; aF32 = 0;
    BT = value + ((long)(j >> 4) << 20); ldBT = 1024; bF32 = 1;
    C = vTp + ((long)(j >> 4) << 16); ldC = 1024; bias = bv; biasM = 1;
  }

  f32x4 acc[4];
#pragma unroll
  for (int nb = 0; nb < 4; ++nb) acc[nb] = (f32x4){0.f, 0.f, 0.f, 0.f};

  stage64(sA[0], aF32 ? (const void*)((const float*)A + (long)m0 * ldA)
                      : (const void*)((const bf16*)A + (long)m0 * ldA), ldA, aF32);
  stage64(sB[0], bF32 ? (const void*)((const float*)BT + (long)n0 * ldBT)
                      : (const void*)((const bf16*)BT + (long)n0 * ldBT), ldBT, bF32);
  __syncthreads();

  for (int it = 0; it < 16; ++it) {
    const int p = it & 1;
    if (it < 15) {
      const int kk = (it + 1) * 64;
      stage64(sA[p ^ 1], aF32 ? (const void*)((const float*)A + (long)m0 * ldA + kk)
                              : (const void*)((const bf16*)A + (long)m0 * ldA + kk), ldA, aF32);
      stage64(sB[p ^ 1], bF32 ? (const void*)((const float*)BT + (long)n0 * ldBT + kk)
                              : (const void*)((const bf16*)BT + (long)n0 * ldBT + kk), ldBT, bF32);
    }
#pragma unroll
    for (int ks = 0; ks < 2; ++ks) {
      const bf16x8 af = frag_ld(sA[p], 16 * w + (lane & 15), ks * 32);
#pragma unroll
      for (int nb = 0; nb < 4; ++nb) {
        const bf16x8 bfr = frag_ld(sB[p], nb * 16 + (lane & 15), ks * 32);
        acc[nb] = __builtin_amdgcn_mfma_f32_16x16x32_bf16(af, bfr, acc[nb], 0, 0, 0);
      }
    }
    __syncthreads();
  }

  const int rbase = m0 + 16 * w + ((lane >> 4) << 2);
#pragma unroll
  for (int nb = 0; nb < 4; ++nb) {
    const int col = n0 + nb * 16 + (lane & 15);
    const float bn = biasM ? 0.f : bias[col];
#pragma unroll
    for (int r = 0; r < 4; ++r) {
      const int row = rbase + r;
      C[(long)row * ldC + col] = (bf16)(acc[nb][r] + (biasM ? bias[row] : bn));
    }
  }
}

// ---------------- combine GEMM: split-K=4 partials + reduce ----------------
__global__ __launch_bounds__(256) void combine_kernel(
    const bf16* __restrict__ concat, const bf16* __restrict__ WcT,
    float* __restrict__ part) {
  const int ks = blockIdx.x >> 6;
  const int m0 = (blockIdx.x & 63) * 64;
  const int k0 = ks * 256;
  __shared__ bf16 sA[2][4096];
  __shared__ bf16 sB[2][4096];
  const int lane = threadIdx.x & 63;
  const int w = threadIdx.x >> 6;

  f32x4 acc[4];
#pragma unroll
  for (int nb = 0; nb < 4; ++nb) acc[nb] = (f32x4){0.f, 0.f, 0.f, 0.f};

  stage64(sA[0], concat + (long)m0 * 1024 + k0, 1024, 0);
  stage64(sB[0], WcT + k0, 1024, 0);
  __syncthreads();
  for (int it = 0; it < 4; ++it) {
    const int p = it & 1;
    if (it < 3) {
      const int kk = k0 + (it + 1) * 64;
      stage64(sA[p ^ 1], concat + (long)m0 * 1024 + kk, 1024, 0);
      stage64(sB[p ^ 1], WcT + kk, 1024, 0);
    }
#pragma unroll
    for (int ksl = 0; ksl < 2; ++ksl) {
      const bf16x8 af = frag_ld(sA[p], 16 * w + (lane & 15), ksl * 32);
#pragma unroll
      for (int nb = 0; nb < 4; ++nb) {
        const bf16x8 bfr = frag_ld(sB[p], nb * 16 + (lane & 15), ksl * 32);
        acc[nb] = __builtin_amdgcn_mfma_f32_16x16x32_bf16(af, bfr, acc[nb], 0, 0, 0);
      }
    }
    __syncthreads();
  }
  const int rbase = m0 + 16 * w + ((lane >> 4) << 2);
  float* pb = part + (long)ks * 262144;
#pragma unroll
  for (int nb = 0; nb < 4; ++nb) {
    const int col = nb * 16 + (lane & 15);
#pragma unroll
    for (int r = 0; r < 4; ++r)
      pb[(long)(rbase + r) * 64 + col] = acc[nb][r];
  }
}

__global__ __launch_bounds__(256) void reduce_combine(
    const float* __restrict__ part, const float* __restrict__ bc,
    float* __restrict__ out0) {
  const int i = blockIdx.x * 256 + threadIdx.x;
  out0[i] = part[i] + part[i + 262144] + part[i + 524288] + part[i + 786432]
          + bc[i & 63];
}

// ---------------- fused attention (R13 champion, exact restore) -----------
// 1024 blocks, 2 waves x 32 q-rows. LDS: 4 x 4KB buffers (32KB).
// Pass A: K-only 4-buffer ring, prefetch 3, counted vmcnt. Pass B: 2-deep
// K+V (bufs 0|1 = K, 2|3 = V), attn stores float via counted vmcnt("8").
__global__ __launch_bounds__(128, 4) void attn_kernel(
    const bf16* __restrict__ q_cat, const bf16* __restrict__ k_proj,
    const bf16* __restrict__ vT, float* __restrict__ attn_out,
    bf16* __restrict__ concat) {
  const int s0 = blockIdx.x * 64;
  const int h = blockIdx.y, b = blockIdx.z;
  const int t = threadIdx.x;               // 0..127
  const int lane = t & 63;
  const int w = t >> 6;                    // 0,1

  __shared__ bf16 sKV[4][4096];

  const bf16* kp = k_proj + (long)b * Sc * DKc;
  const bf16* vp = vT + (long)b * DKc * Sc;
  float* ao = attn_out + ((long)(b * Hc + h) * Sc + s0) * Sc;
  bf16* co = concat + (long)(b * Sc + s0) * (Hc * DKc) + h * DKc;

  const int c0q = (lane >> 4) << 2;
  const int wq0 = w * 32;

  const int rloc = t >> 3;
  const int col8 = ((t & 7) ^ (rloc & 7)) << 3;
  const int ldsw = w << 9;

  auto stageK = [&](int buf, int tt) {     // 4 DMAs per wave
#pragma unroll
    for (int c = 0; c < 4; ++c)
      gld16(kp + ((long)tt << 12) + (c * 16 + rloc) * 64 + col8,
            &sKV[buf][c * 1024 + ldsw]);
  };
  auto stageV = [&](int buf, int tt) {     // 4 DMAs per wave
#pragma unroll
    for (int c = 0; c < 4; ++c)
      gld16(vp + (long)(c * 16 + rloc) * 1024 + tt * 64 + col8,
            &sKV[buf][c * 1024 + ldsw]);
  };

  // Q fragments for both q-groups (pre-scaled by ESCALE via WqT)
  bf16x8 qf[2][2];
#pragma unroll
  for (int qg = 0; qg < 2; ++qg) {
    const bf16* qrow = q_cat + (long)(b * Sc + s0 + wq0 + qg * 16 + (lane & 15)) * 1024 + h * 64;
    union { bf16x8 v8; bf16x4 v4[2]; } a, c;
    a.v4[0] = *(const bf16x4*)(qrow + c0q);
    a.v4[1] = *(const bf16x4*)(qrow + c0q + 16);
    c.v4[0] = *(const bf16x4*)(qrow + c0q + 32);
    c.v4[1] = *(const bf16x4*)(qrow + c0q + 48);
    qf[qg][0] = a.v8; qf[qg][1] = c.v8;
  }

  // ---- pass A: lsum only; 4-ring, prefetch depth 3 ----
  stageK(0, 0); stageK(1, 1); stageK(2, 2);
  WAIT_BAR("8");                           // 12 out -> <=8: batch 0 retired
  float lsum[2] = {0.f, 0.f};
  for (int tc = 0; tc < 16; ++tc) {
    if (tc + 3 < 16) stageK((tc + 3) & 3, tc + 3);
    const bf16* kb = &sKV[tc & 3][0];
    bf16x8 kf[2][4];
#pragma unroll
    for (int ks = 0; ks < 2; ++ks)
#pragma unroll
      for (int nb = 0; nb < 4; ++nb)
        kf[ks][nb] = frag_ld(kb, nb * 16 + (lane & 15), ks * 32);
#pragma unroll
    for (int qg = 0; qg < 2; ++qg) {
      f32x4 sc[4];
#pragma unroll
      for (int nb = 0; nb < 4; ++nb) sc[nb] = (f32x4){0.f, 0.f, 0.f, 0.f};
#pragma unroll
      for (int ks = 0; ks < 2; ++ks)
#pragma unroll
        for (int nb = 0; nb < 4; ++nb)
          sc[nb] = __builtin_amdgcn_mfma_f32_16x16x32_bf16(kf[ks][nb], qf[qg][ks], sc[nb], 0, 0, 0);
#pragma unroll
      for (int nb = 0; nb < 4; ++nb)
#pragma unroll
        for (int r = 0; r < 4; ++r) lsum[qg] += EXP2F(sc[nb][r]);
    }
    // need buf (tc+1) ready next iter: allow only batches > tc+1 in flight
    if (tc < 13)       WAIT_BAR("8");
    else if (tc == 13) WAIT_BAR("4");
    else if (tc == 14) WAIT_BAR("0");
  }
  __builtin_amdgcn_s_barrier();            // pass A fully done before re-staging

#pragma unroll
  for (int qg = 0; qg < 2; ++qg) {
    lsum[qg] += __shfl_xor(lsum[qg], 16, 64);
    lsum[qg] += __shfl_xor(lsum[qg], 32, 64);
  }
  const float invl0 = 1.f / lsum[0], invl1 = 1.f / lsum[1];

  f32x4 oacc[2][4];
#pragma unroll
  for (int qg = 0; qg < 2; ++qg)
#pragma unroll
    for (int nb = 0; nb < 4; ++nb) oacc[qg][nb] = (f32x4){0.f, 0.f, 0.f, 0.f};

  // ---- pass B: recompute, store attn (floating via counted vmcnt), PV ----
  // buffers: K in sKV[0|1], V in sKV[2|3]
  stageK(0, 0);
  stageV(2, 0);
  WAIT_BAR("0");
  for (int tc = 0; tc < 16; ++tc) {
    const int p = tc & 1;
    if (tc < 15) { stageK(p ^ 1, tc + 1); stageV(2 + (p ^ 1), tc + 1); }
    bf16x8 kf[2][4];
#pragma unroll
    for (int ks = 0; ks < 2; ++ks)
#pragma unroll
      for (int nb = 0; nb < 4; ++nb)
        kf[ks][nb] = frag_ld(&sKV[p][0], nb * 16 + (lane & 15), ks * 32);
    bf16x8 pa[2][2];
#pragma unroll
    for (int qg = 0; qg < 2; ++qg) {
      f32x4 sc[4];
#pragma unroll
      for (int nb = 0; nb < 4; ++nb) sc[nb] = (f32x4){0.f, 0.f, 0.f, 0.f};
#pragma unroll
      for (int ks = 0; ks < 2; ++ks)
#pragma unroll
        for (int nb = 0; nb < 4; ++nb)
          sc[nb] = __builtin_amdgcn_mfma_f32_16x16x32_bf16(kf[ks][nb], qf[qg][ks], sc[nb], 0, 0, 0);
      const float invl = qg ? invl1 : invl0;
      float* aobase = ao + (long)(wq0 + qg * 16 + (lane & 15)) * Sc + tc * 64 + c0q;
      float e[4][4];
#pragma unroll
      for (int nb = 0; nb < 4; ++nb) {
#pragma unroll
        for (int r = 0; r < 4; ++r) e[nb][r] = EXP2F(sc[nb][r]);
        f32x4 av;
#pragma unroll
        for (int r = 0; r < 4; ++r) av[r] = e[nb][r] * invl;
        *(f32x4*)(aobase + nb * 16) = av;
      }
#pragma unroll
      for (int ks = 0; ks < 2; ++ks)
#pragma unroll
        for (int jj = 0; jj < 4; ++jj) {
          pa[qg][ks][jj]     = (bf16)e[2 * ks][jj];
          pa[qg][ks][4 + jj] = (bf16)e[2 * ks + 1][jj];
        }
    }
#pragma unroll
    for (int ks = 0; ks < 2; ++ks)
#pragma unroll
      for (int nb = 0; nb < 4; ++nb) {
        const bf16x8 vf = frag_ld(&sKV[2 + p][0], nb * 16 + (lane & 15), ks * 32);
        oacc[0][nb] = __builtin_amdgcn_mfma_f32_16x16x32_bf16(pa[0][ks], vf, oacc[0][nb], 0, 0, 0);
        oacc[1][nb] = __builtin_amdgcn_mfma_f32_16x16x32_bf16(pa[1][ks], vf, oacc[1][nb], 0, 0, 0);
      }
    if (tc < 15) WAIT_BAR("8");            // drain the 8 DMAs; stores float
  }

  // epilogue: normalize PV, store concat slice
#pragma unroll
  for (int qg = 0; qg < 2; ++qg) {
    const float invl = qg ? invl1 : invl0;
    float invo[4];
#pragma unroll
    for (int r = 0; r < 4; ++r) invo[r] = __shfl(invl, c0q + r, 64);
#pragma unroll
    for (int nb = 0; nb < 4; ++nb) {
#pragma unroll
      for (int r = 0; r < 4; ++r) {
        const int row = wq0 + qg * 16 + c0q + r;
        const int col = nb * 16 + (lane & 15);
        co[(long)row * (Hc * DKc) + col] = (bf16)(oacc[qg][nb][r] * invo[r]);
      }
    }
  }
}

// ---------------- launcher ----------------

extern "C" void kernel_launch(void* const* d_in, const int* in_sizes, int n_in,
                              void* d_out, int out_size, void* d_ws, size_t ws_size,
                              hipStream_t stream) {
  const float* query = (const float*)d_in[0];
  const float* key   = (const float*)d_in[1];
  const float* value = (const float*)d_in[2];
  const float* Wq = (const float*)d_in[3];
  const float* bq = (const float*)d_in[4];
  const float* Wk = (const float*)d_in[5];
  const float* bk = (const float*)d_in[6];
  const float* Wv = (const float*)d_in[7];
  const float* bv = (const float*)d_in[8];
  const float* Wc = (const float*)d_in[9];
  const float* bc = (const float*)d_in[10];

  bf16* WqT    = (bf16*)d_ws;              // [1024][1024] (pre-scaled ESCALE)
  bf16* WkT    = WqT + 1048576;            // [64][1024]
  bf16* WvT    = WkT + 65536;
  bf16* WcT    = WvT + 65536;              // [64][1024]
  bf16* q_cat  = WcT + 65536;              // [4096][1024]
  bf16* k_proj = q_cat + 4194304;          // [4096][64]
  bf16* vTp    = k_proj + 262144;          // [B][64][1024]
  bf16* concat = vTp + 262144;             // [4096][1024]
  float* part  = (float*)(concat + 4194304); // [4][4096][64] fp32 partials

  float* out0 = (float*)d_out;                       // [B][S][DK]
  float* attn = out0 + (long)Bc * Sc * DKc;          // [B][H][S][S]

  transpose_weights<<<304, 256, 0, stream>>>(Wq, Wk, Wv, Wc, WqT, WkT, WvT, WcT);

  proj_kernel<<<384, 256, 0, stream>>>(query, key, value, WqT, WkT, WvT,
                                       bq, bk, bv, q_cat, k_proj, vTp);

  attn_kernel<<<dim3(16, 16, 4), 128, 0, stream>>>(q_cat, k_proj, vTp, attn, concat);

  combine_kernel<<<256, 256, 0, stream>>>(concat, WcT, part);
  reduce_combine<<<1024, 256, 0, stream>>>(part, bc, out0);
}